// Round 9
// baseline (275.660 us; speedup 1.0000x reference)
//
#include <hip/hip_runtime.h>
#include <hip/hip_bf16.h>
#include <hip/hip_fp8.h>

// SNN forward, round 9: BARRIER-FREE per-wave GEMM.
//   Each wave independently computes a 64(t) x 64(h) tile of iff for one
//   batch row: A = x[b][t0+tt*64 .. +64][:] f32 direct global->reg + cvt_pk,
//   B = w1frag (bf16 fragment-ordered, 1KB wave-contiguous loads, L2-hit).
//   No LDS, no __syncthreads. 1-deep named-register prefetch, per-wave
//   K-rotation to spread L2 traffic. fp8 epilogue (pre-scaled by 1-alpha),
//   permuted within 64-col chunks -> u32 stores; recur compensates (hstoremap).

#define B_    256
#define T_    250
#define NIN   700
#define NHID  512
#define NOUT  20
#define NKT   22          // K-tiles of 32 (704 = 22*32, zero-padded)

typedef __attribute__((ext_vector_type(8))) short short8;
typedef __attribute__((ext_vector_type(4))) float f32x4;

static __device__ __forceinline__ ushort f2bf(float f) {
  union { float f; unsigned u; } v; v.f = f;
  unsigned r = (v.u + 0x7FFF + ((v.u >> 16) & 1)) >> 16;  // RNE
  return (ushort)r;
}
static __device__ __forceinline__ unsigned cvtpk_bf16(float a, float b) {
  unsigned r;
  asm("v_cvt_pk_bf16_f32 %0, %1, %2" : "=v"(r) : "v"(a), "v"(b));
  return r;
}
// storage slot s (0..511) -> actual hidden unit h (within-64 inner permutation)
static __device__ __forceinline__ int hstoremap(int s) {
  return (s & 0x1C0) | ((s & 3) << 4) | ((s >> 2) & 15);
}

// ---------------- prep: w1 -> bf16 fragment chunks ----------------
// chunk (cb64, kt): 4KB = [j 0..3][lane 0..63][8 bf16]
// col = cb64*64 + j*16 + (lane&15); k = kt*32 + (lane>>4)*8 + e
__global__ __launch_bounds__(256) void prep_kernel(
    const float* __restrict__ w1, ushort* __restrict__ w1frag) {
  int i = blockIdx.x * 256 + threadIdx.x;
  if (i >= 8 * NKT * 2048) return;
  int e     = i & 7;
  int lane  = (i >> 3) & 63;
  int j     = (i >> 9) & 3;
  int chunk = i >> 11;
  int cb = chunk / NKT, kt = chunk - cb * NKT;
  int col = cb * 64 + j * 16 + (lane & 15);
  int k   = kt * 32 + (lane >> 4) * 8 + e;
  w1frag[i] = (k < NIN) ? f2bf(w1[(size_t)col * NIN + k]) : (ushort)0;
}

// ---------------- barrier-free per-wave MFMA GEMM ----------------
// wave g = blockIdx.x*4 + wave; c = g&7 (64-col block), mt = g>>3;
// b = mt/ntt, tt = mt%ntt (64-t tile). No LDS, no barriers.
__global__ __launch_bounds__(256, 3) void gemm_wave(
    const float* __restrict__ x, const ushort* __restrict__ w1frag,
    const float* __restrict__ alpha, unsigned char* __restrict__ iff,
    int t0, int tc, int ntt) {
  int tid = threadIdx.x, lane = tid & 63, wave = tid >> 6;
  int g  = blockIdx.x * 4 + wave;
  int c  = g & 7;
  int mt = g >> 3;
  int b  = mt / ntt;
  int tt = mt - b * ntt;
  int lm = lane & 15, lk = lane >> 4;
  int trow0 = tt * 64;

  const float* arow[4];
  bool rowok[4];
#pragma unroll
  for (int i = 0; i < 4; ++i) {
    int tr = trow0 + i * 16 + lm;
    rowok[i] = tr < tc;
    arow[i] = x + ((size_t)b * T_ + t0 + (rowok[i] ? tr : 0)) * NIN;
  }
  const float4 fz_ = (float4){0.f, 0.f, 0.f, 0.f};

  f32x4 acc[4][4];
#pragma unroll
  for (int i = 0; i < 4; ++i)
#pragma unroll
    for (int j = 0; j < 4; ++j) acc[i][j] = (f32x4){0.f, 0.f, 0.f, 0.f};

  float4 rA[8];
  short8 fAa[4], fAb[4], fBa[4], fBb[4];

#define LOADB(FB, KT) do {                                                   \
    const char* bp_ = (const char*)w1frag                                    \
                    + ((size_t)((c * NKT + (KT)) << 12)) + lane * 16;        \
    _Pragma("unroll")                                                        \
    for (int j_ = 0; j_ < 4; ++j_)                                           \
      FB[j_] = *(const short8*)(bp_ + j_ * 1024);                            \
  } while (0)

#define LOADAF(KT) do { int k0_ = (KT) * 32 + lk * 8;                        \
    _Pragma("unroll")                                                        \
    for (int i_ = 0; i_ < 4; ++i_) {                                         \
      rA[2*i_]   = rowok[i_] ? *(const float4*)(arow[i_] + k0_) : fz_;       \
      rA[2*i_+1] = (rowok[i_] && k0_ + 8 <= NIN)                             \
                   ? *(const float4*)(arow[i_] + k0_ + 4) : fz_;             \
    } } while (0)

#define CVTA(FA) do { _Pragma("unroll")                                     \
    for (int i_ = 0; i_ < 4; ++i_) {                                         \
      union { unsigned u[4]; short8 s; } t_;                                 \
      t_.u[0] = cvtpk_bf16(rA[2*i_].x,   rA[2*i_].y);                        \
      t_.u[1] = cvtpk_bf16(rA[2*i_].z,   rA[2*i_].w);                        \
      t_.u[2] = cvtpk_bf16(rA[2*i_+1].x, rA[2*i_+1].y);                      \
      t_.u[3] = cvtpk_bf16(rA[2*i_+1].z, rA[2*i_+1].w);                      \
      FA[i_] = t_.s; } } while (0)

#define MFMA16(FA, FB) do { _Pragma("unroll")                                \
    for (int i_ = 0; i_ < 4; ++i_)                                           \
      _Pragma("unroll")                                                      \
      for (int j_ = 0; j_ < 4; ++j_)                                         \
        acc[i_][j_] = __builtin_amdgcn_mfma_f32_16x16x32_bf16(               \
            FA[i_], FB[j_], acc[i_][j_], 0, 0, 0);                           \
  } while (0)

  // per-wave K-rotation: desynchronize shared-B L2 access
  int ks = (int)(((unsigned)(mt * 5 + c)) % NKT);

  int kc = ks;
  LOADB(fBa, kc);
  LOADAF(kc);
  CVTA(fAa);
  for (int it2 = 0; it2 < 11; ++it2) {
    int k1 = kc + 1; if (k1 >= NKT) k1 -= NKT;
    LOADB(fBb, k1);
    LOADAF(k1);
    MFMA16(fAa, fBa);
    CVTA(fAb);
    int k2 = k1 + 1; if (k2 >= NKT) k2 -= NKT;
    if (it2 < 10) { LOADB(fBa, k2); LOADAF(k2); }
    MFMA16(fAb, fBb);
    if (it2 < 10) CVTA(fAa);
    kc = k2;
  }
#undef LOADB
#undef LOADAF
#undef CVTA
#undef MFMA16

  // epilogue: scale by (1-alpha[col]); pack 4 fp8 (j=0..3) into one u32 at
  // permuted slot c*64 + lm*4 (byte j <-> col c*64 + j*16 + lm = hstoremap).
  float scl[4];
#pragma unroll
  for (int j = 0; j < 4; ++j)
    scl[j] = 1.0f - alpha[c * 64 + j * 16 + lm];
#pragma unroll
  for (int i = 0; i < 4; ++i) {
#pragma unroll
    for (int r = 0; r < 4; ++r) {
      int trow = trow0 + i * 16 + lk * 4 + r;
      if (trow < tc) {
        unsigned u = 0;
#pragma unroll
        for (int j = 0; j < 4; ++j) {
          __hip_fp8_e4m3 q(acc[i][j][r] * scl[j]);
          u |= ((unsigned)q.__x) << (8 * j);
        }
        *(unsigned*)(iff + ((size_t)b * tc + trow) * NHID + c * 64 + lm * 4) = u;
      }
    }
  }
}

// ---------------- fused recurrence (unchanged from R8) ----------------
__global__ __launch_bounds__(64) void snn_recur(
    const unsigned char* __restrict__ iff, const float* __restrict__ wrec,
    const float* __restrict__ wout,
    const float* __restrict__ alpha, const float* __restrict__ rho,
    const float* __restrict__ beta_a, const float* __restrict__ beta_out,
    float* __restrict__ state, int* __restrict__ flags,
    float* __restrict__ dout, int Tc, int first, int last) {
  int lane = threadIdx.x;
  int b = blockIdx.x;
  int hbase = lane * 8;
  const unsigned char* ib = iff + (size_t)b * Tc * NHID + hbase;

  float* v1s = state;
  float* a1s = state + B_ * NHID;
  float* sps = state + 2 * B_ * NHID;
  float* vos = state + 3 * B_ * NHID;
  float* oss = vos + B_ * NOUT;

  int hact[8];
#pragma unroll
  for (int r = 0; r < 8; ++r) hact[r] = hstoremap(hbase + r);

  float v1[8], a1[8], sp[8], al[8], rh[8], ba[8];
#pragma unroll
  for (int r = 0; r < 8; ++r) {
    int h = hact[r];
    al[r] = alpha[h]; rh[r] = rho[h]; ba[r] = beta_a[h];
    if (first) { v1[r] = 0.f; a1[r] = 0.f; sp[r] = 0.f; }
    else {
      v1[r] = v1s[(size_t)b * NHID + hbase + r];
      a1[r] = a1s[(size_t)b * NHID + hbase + r];
      sp[r] = sps[(size_t)b * NHID + hbase + r];
    }
  }
  float vout = 0.f, osum = 0.f, bo = 0.f;
  if (lane < NOUT) {
    bo = beta_out[lane];
    if (!first) { vout = vos[b * NOUT + lane]; osum = oss[b * NOUT + lane]; }
  }

  int mode = first ? 0 : flags[b];
  int tle = 0;

  if (mode == 0) {
    // fast path: no spike has ever fired
    uint2 pf[8];
#pragma unroll
    for (int j = 0; j < 8; ++j) {
      int tl = (j < Tc) ? j : (Tc - 1);
      pf[j] = *(const uint2*)(ib + (size_t)tl * NHID);
    }
    bool esc = false;
    for (int tb = 0; tb < Tc && !esc; tb += 8) {
#pragma unroll
      for (int j = 0; j < 8; ++j) {
        int tl = tb + j;
        if (!esc && tl < Tc) {
          float tv[8];
#pragma unroll
          for (int r = 0; r < 8; ++r) {
            unsigned w = (r < 4) ? pf[j].x : pf[j].y;
            __hip_fp8_e4m3 q; q.__x = (unsigned char)((w >> ((r & 3) * 8)) & 255u);
            tv[r] = al[r] * v1[r] + (float)q;   // iff pre-scaled by (1-alpha)
          }
          float m01 = fmaxf(tv[0], tv[1]), m23 = fmaxf(tv[2], tv[3]);
          float m45 = fmaxf(tv[4], tv[5]), m67 = fmaxf(tv[6], tv[7]);
          float mx = fmaxf(fmaxf(m01, m23), fmaxf(m45, m67));
          if (__ballot(mx > 1.0f)) {
            esc = true; tle = tl;
          } else {
#pragma unroll
            for (int r = 0; r < 8; ++r) v1[r] = tv[r];
            int nt = (tl + 8 < Tc) ? (tl + 8) : (Tc - 1);
            pf[j] = *(const uint2*)(ib + (size_t)nt * NHID);
          }
        }
      }
    }
    if (!esc) tle = Tc;
    mode = esc ? 1 : 0;
  }

  // full path (fallback / post-first-spike)
  unsigned long long mask[8];
#pragma unroll
  for (int r = 0; r < 8; ++r) mask[r] = __ballot(sp[r] != 0.f);

  for (int tl = tle; tl < Tc; ++tl) {
    uint2 w2 = *(const uint2*)(ib + (size_t)tl * NHID);
    float iv[8];
#pragma unroll
    for (int r = 0; r < 8; ++r) {
      unsigned w = (r < 4) ? w2.x : w2.y;
      __hip_fp8_e4m3 q; q.__x = (unsigned char)((w >> ((r & 3) * 8)) & 255u);
      iv[r] = (float)q;   // = (1-alpha)*i_ff
    }
    unsigned long long anyp = mask[0] | mask[1] | mask[2] | mask[3] |
                              mask[4] | mask[5] | mask[6] | mask[7];
    if (anyp) {
      float rec[8] = {0.f,0.f,0.f,0.f,0.f,0.f,0.f,0.f};
#pragma unroll
      for (int r2 = 0; r2 < 8; ++r2) {
        unsigned long long mm = mask[r2];
        while (mm) {
          int l2 = __ffsll(mm) - 1; mm &= (mm - 1);
          int hp = hstoremap(l2 * 8 + r2);
#pragma unroll
          for (int r = 0; r < 8; ++r)
            rec[r] += wrec[(size_t)hact[r] * NHID + hp];
        }
      }
#pragma unroll
      for (int r = 0; r < 8; ++r) iv[r] += (1.0f - al[r]) * rec[r];
    }

    float s[8];
#pragma unroll
    for (int r = 0; r < 8; ++r) {
      a1[r] = rh[r] * a1[r] + ba[r] * sp[r];
      v1[r] = al[r] * v1[r] + iv[r] - a1[r];
      s[r] = (v1[r] - 1.0f > 0.0f) ? 1.0f : 0.0f;
      v1[r] -= s[r];
      sp[r] = s[r];
      mask[r] = __ballot(s[r] != 0.f);
    }

    unsigned long long anyc = mask[0] | mask[1] | mask[2] | mask[3] |
                              mask[4] | mask[5] | mask[6] | mask[7];
    if (lane < NOUT) {
      float io = 0.f;
      if (anyc) {
#pragma unroll
        for (int r2 = 0; r2 < 8; ++r2) {
          unsigned long long mm = mask[r2];
          while (mm) {
            int l2 = __ffsll(mm) - 1; mm &= (mm - 1);
            int hp = hstoremap(l2 * 8 + r2);
            io += wout[(size_t)lane * NHID + hp];
          }
        }
      }
      vout = bo * vout + (1.0f - bo) * io;
      float so = (vout - 1.0f > 0.0f) ? 1.0f : 0.0f;
      vout -= so;
      osum += vout;
    }
  }

  if (last) {
    if (lane < NOUT) dout[b * NOUT + lane] = osum / (float)T_;
  } else {
#pragma unroll
    for (int r = 0; r < 8; ++r) {
      v1s[(size_t)b * NHID + hbase + r] = v1[r];
      a1s[(size_t)b * NHID + hbase + r] = a1[r];
      sps[(size_t)b * NHID + hbase + r] = sp[r];
    }
    if (lane < NOUT) { vos[b * NOUT + lane] = vout; oss[b * NOUT + lane] = osum; }
    if (lane == 0) flags[b] = mode;
  }
}

extern "C" void kernel_launch(void* const* d_in, const int* in_sizes, int n_in,
                              void* d_out, int out_size, void* d_ws, size_t ws_size,
                              hipStream_t stream) {
  const float* x      = (const float*)d_in[0];
  const float* w1     = (const float*)d_in[1];
  const float* wrec   = (const float*)d_in[2];
  const float* wout   = (const float*)d_in[3];
  const float* alpha  = (const float*)d_in[4];
  const float* rho    = (const float*)d_in[5];
  const float* beta_a = (const float*)d_in[6];
  const float* bout   = (const float*)d_in[7];
  float* out = (float*)d_out;

  char* ws = (char*)d_ws;
  const size_t w1frag_bytes = (size_t)8 * NKT * 2048 * 2;                    // 704 KB
  const size_t state_off = w1frag_bytes;
  const size_t state_bytes = (size_t)(3 * B_ * NHID + 2 * B_ * NOUT) * 4;
  const size_t flags_off = state_off + state_bytes;
  const size_t iff_off   = flags_off + B_ * 4;

  ushort* w1frag = (ushort*)(ws);
  float*  statep = (float*)(ws + state_off);
  int*    flagsp = (int*)(ws + flags_off);
  unsigned char* iff = (unsigned char*)(ws + iff_off);

  const size_t per_step = (size_t)B_ * NHID;  // 128 KB per timestep (fp8)
  long long avail = (long long)ws_size - (long long)iff_off;
  int Tc = (int)(avail / (long long)per_step);
  if (Tc > T_) Tc = T_;
  if (Tc < 1) Tc = 1;

  prep_kernel<<<dim3((8 * NKT * 2048 + 255) / 256), dim3(256), 0, stream>>>(
      w1, w1frag);

  for (int t0 = 0; t0 < T_; t0 += Tc) {
    int tc = (T_ - t0 < Tc) ? (T_ - t0) : Tc;
    int ntt = (tc + 63) >> 6;
    gemm_wave<<<dim3(512 * ntt), dim3(256), 0, stream>>>(
        x, w1frag, alpha, iff, t0, tc, ntt);
    snn_recur<<<dim3(B_), dim3(64), 0, stream>>>(
        iff, wrec, wout, alpha, rho, beta_a, bout, statep, flagsp, out,
        tc, (t0 == 0) ? 1 : 0, (t0 + tc >= T_) ? 1 : 0);
  }
}

// Round 10
// 140.760 us; speedup vs baseline: 1.9584x; 1.9584x over previous
//
#include <hip/hip_runtime.h>
#include <hip/hip_bf16.h>
#include <hip/hip_fp8.h>

// SNN forward, round 10: A-resident streaming GEMM.
//   Block = 64 consecutive m-rows (m = b*tc+t -> x rows are CONTIGUOUS).
//   A: 64x704 bf16 (88KB) write-once in LDS, staged incrementally during the
//   K-loop (load even-iter, cvt+write odd-iter, 3-tile lookahead). B: 32KB
//   k-tile double-buffer via global_load_lds, counted vmcnt(2) (B issued
//   before A so the count drains exactly B). 8 waves, wave-tile 64x64,
//   16 MFMA + 8 fragment-ordered conflict-free ds_read_b128 per iteration,
//   ONE barrier/iter. 1 block/CU, x read exactly once per block.

#define B_    256
#define T_    250
#define NIN   700
#define NHID  512
#define NOUT  20
#define NKT   22          // K-tiles of 32 (704 = 22*32, zero-padded)

typedef __attribute__((ext_vector_type(8))) short short8;
typedef __attribute__((ext_vector_type(4))) float f32x4;

static __device__ __forceinline__ ushort f2bf(float f) {
  union { float f; unsigned u; } v; v.f = f;
  unsigned r = (v.u + 0x7FFF + ((v.u >> 16) & 1)) >> 16;  // RNE
  return (ushort)r;
}
static __device__ __forceinline__ unsigned cvtpk_bf16(float a, float b) {
  unsigned r;
  asm("v_cvt_pk_bf16_f32 %0, %1, %2" : "=v"(r) : "v"(a), "v"(b));
  return r;
}
static __device__ __forceinline__ void gload_lds16(const void* g, void* l) {
  __builtin_amdgcn_global_load_lds(
      (const __attribute__((address_space(1))) unsigned*)g,
      (__attribute__((address_space(3))) unsigned*)l, 16, 0, 0);
}
// storage slot s (0..511) -> actual hidden unit h (within-64 inner permutation)
static __device__ __forceinline__ int hstoremap(int s) {
  return (s & 0x1C0) | ((s & 3) << 4) | ((s >> 2) & 15);
}

// ---------------- prep: w1 -> bf16 fragment slabs ----------------
// slab kt (32KB): [cb 0..31][lane 0..63][8 bf16]
// col = cb*16 + (lane&15); k = kt*32 + (lane>>4)*8 + e
__global__ __launch_bounds__(256) void prep_kernel(
    const float* __restrict__ w1, ushort* __restrict__ w1frag) {
  int i = blockIdx.x * 256 + threadIdx.x;
  if (i >= NKT * 16384) return;
  int e    = i & 7;
  int lane = (i >> 3) & 63;
  int cb   = (i >> 9) & 31;
  int kt   = i >> 14;
  int col = cb * 16 + (lane & 15);
  int k   = kt * 32 + (lane >> 4) * 8 + e;
  w1frag[i] = (k < NIN) ? f2bf(w1[(size_t)col * NIN + k]) : (ushort)0;
}

// ---------------- A-resident MFMA GEMM ----------------
// grid = 4*tc blocks of 512 thr (8 waves); block handles m-rows m0..m0+63,
// all 512 h-columns. Wave w owns cols w*64..w*64+63.
__global__ __launch_bounds__(512) void gemm_mfma(
    const float* __restrict__ x, const ushort* __restrict__ w1frag,
    const float* __restrict__ alpha, unsigned char* __restrict__ iff,
    int t0, int tc) {
  __shared__ __align__(16) char Al[88 * 1024];   // 88 groups x 1KB (frag order)
  __shared__ __align__(16) char Bl[2][32768];

  int tid = threadIdx.x, lane = tid & 63, wave = tid >> 6;
  int lm = lane & 15, lk = lane >> 4;
  int m0 = blockIdx.x * 64;

  // stager: thread -> (row srow 0..63, octet-slot soct 0..7)
  int srow = tid >> 3, soct = tid & 7;
  int m = m0 + srow;
  int b = m / tc;                 // one div per thread
  int tl = m - b * tc;
  const float* ap = x + ((size_t)b * T_ + t0 + tl) * NIN;
  const float4 fz = (float4){0.f, 0.f, 0.f, 0.f};

  f32x4 acc[4][4];
#pragma unroll
  for (int i = 0; i < 4; ++i)
#pragma unroll
    for (int j = 0; j < 4; ++j) acc[i][j] = (f32x4){0.f, 0.f, 0.f, 0.f};

  // A line write: (srow, global octet GOCT) <- 8 bf16 from FA,FB
  // group g = (GOCT>>2)*4 + (srow>>4); lane-slot l = (srow&15) | ((GOCT&3)<<4)
#define WRLINE(GOCT, FA, FB) do {                                            \
    uint4 pk_;                                                               \
    pk_.x = cvtpk_bf16(FA.x, FA.y); pk_.y = cvtpk_bf16(FA.z, FA.w);          \
    pk_.z = cvtpk_bf16(FB.x, FB.y); pk_.w = cvtpk_bf16(FB.z, FB.w);          \
    int g_ = (((GOCT) >> 2) * 4 + (srow >> 4));                              \
    int l_ = (srow & 15) | (((GOCT) & 3) << 4);                              \
    *(uint4*)(&Al[g_ * 1024 + l_ * 16]) = pk_;                               \
  } while (0)

#define LOADX(GOCT, FA, FB) do { int k0_ = (GOCT) * 8;                       \
    FA = (k0_ + 4 <= NIN) ? *(const float4*)(ap + k0_) : fz;                 \
    FB = (k0_ + 8 <= NIN) ? *(const float4*)(ap + k0_ + 4) : fz;             \
  } while (0)

#define STAGEB(BUF, KT) do {                                                 \
    const char* gs_ = (const char*)w1frag + ((size_t)(KT) << 15);            \
    _Pragma("unroll")                                                        \
    for (int c_ = 0; c_ < 4; ++c_) {                                         \
      int off_ = (wave * 4 + c_) * 1024;                                     \
      gload_lds16(gs_ + off_ + lane * 16, &Bl[BUF][off_]);                   \
    } } while (0)

#define DSRD(AF, BF, KT, BUF) do { _Pragma("unroll")                         \
    for (int i_ = 0; i_ < 4; ++i_)                                           \
      AF[i_] = *(const short8*)(&Al[((KT) * 4 + i_) * 1024 + lane * 16]);    \
    _Pragma("unroll")                                                        \
    for (int j_ = 0; j_ < 4; ++j_)                                           \
      BF[j_] = *(const short8*)(&Bl[BUF][(wave * 4 + j_) * 1024 + lane * 16]); \
  } while (0)

#define MFMA16(AF, BF) do {                                                  \
    __builtin_amdgcn_s_setprio(1);                                           \
    _Pragma("unroll")                                                        \
    for (int i_ = 0; i_ < 4; ++i_)                                           \
      _Pragma("unroll")                                                      \
      for (int j_ = 0; j_ < 4; ++j_)                                         \
        acc[i_][j_] = __builtin_amdgcn_mfma_f32_16x16x32_bf16(               \
            AF[i_], BF[j_], acc[i_][j_], 0, 0, 0);                           \
    __builtin_amdgcn_s_setprio(0);                                           \
  } while (0)

  // ---- prologue: A tiles 0..3 (octets 0..15) + B(0) ----
  {
    float4 a0, b0, a1, b1;
    LOADX(soct, a0, b0);
    LOADX(soct + 8, a1, b1);
    STAGEB(0, 0);
    WRLINE(soct, a0, b0);          // cvt auto-waits the A loads
    WRLINE(soct + 8, a1, b1);
    asm volatile("s_waitcnt vmcnt(0) lgkmcnt(0)" ::: "memory");
    __builtin_amdgcn_s_barrier();
    __builtin_amdgcn_sched_barrier(0);
  }

  float4 fa, fb;   // pending A-stream line (loaded even iter, written odd iter)

  for (int kt2 = 0; kt2 < 11; ++kt2) {
    int kte = kt2 * 2;
    // ---------- even iteration (reads Bl[0]) ----------
    {
      STAGEB(1, kte + 1);                       // B(kt+1): 4 vm issued FIRST
      if (kt2 <= 8) LOADX(16 + kt2 * 8 + soct, fa, fb);   // A-stream: 2 vm after
      short8 af[4], bfr[4];
      DSRD(af, bfr, kte, 0);
      MFMA16(af, bfr);
      if (kt2 <= 8)
        asm volatile("s_waitcnt vmcnt(2) lgkmcnt(0)" ::: "memory");  // drain B, keep A
      else
        asm volatile("s_waitcnt vmcnt(0) lgkmcnt(0)" ::: "memory");
      __builtin_amdgcn_s_barrier();
      __builtin_amdgcn_sched_barrier(0);
    }
    // ---------- odd iteration (reads Bl[1]) ----------
    {
      int kto = kte + 1;
      if (kto < 21) STAGEB(0, kto + 1);
      short8 af[4], bfr[4];
      DSRD(af, bfr, kto, 1);
      MFMA16(af, bfr);
      if (kt2 <= 8) WRLINE(16 + kt2 * 8 + soct, fa, fb);  // cvt waits A (1-iter cover)
      if (kto < 21) {
        asm volatile("s_waitcnt vmcnt(0) lgkmcnt(0)" ::: "memory");
        __builtin_amdgcn_s_barrier();
        __builtin_amdgcn_sched_barrier(0);
      }
    }
  }
#undef WRLINE
#undef LOADX
#undef STAGEB
#undef DSRD
#undef MFMA16

  // epilogue: scale by (1-alpha[col]); pack 4 fp8 (j=0..3) into one u32 at
  // permuted slot s = wave*64 + lm*4 + j  <->  h = wave*64 + j*16 + lm.
  float scl[4];
#pragma unroll
  for (int j = 0; j < 4; ++j)
    scl[j] = 1.0f - alpha[wave * 64 + j * 16 + lm];
#pragma unroll
  for (int i = 0; i < 4; ++i) {
#pragma unroll
    for (int r = 0; r < 4; ++r) {
      int mrow = i * 16 + lk * 4 + r;
      unsigned u = 0;
#pragma unroll
      for (int j = 0; j < 4; ++j) {
        __hip_fp8_e4m3 q(acc[i][j][r] * scl[j]);
        u |= ((unsigned)q.__x) << (8 * j);
      }
      *(unsigned*)(iff + (size_t)(m0 + mrow) * NHID + wave * 64 + lm * 4) = u;
    }
  }
}

// ---------------- fused recurrence (unchanged from R8) ----------------
__global__ __launch_bounds__(64) void snn_recur(
    const unsigned char* __restrict__ iff, const float* __restrict__ wrec,
    const float* __restrict__ wout,
    const float* __restrict__ alpha, const float* __restrict__ rho,
    const float* __restrict__ beta_a, const float* __restrict__ beta_out,
    float* __restrict__ state, int* __restrict__ flags,
    float* __restrict__ dout, int Tc, int first, int last) {
  int lane = threadIdx.x;
  int b = blockIdx.x;
  int hbase = lane * 8;
  const unsigned char* ib = iff + (size_t)b * Tc * NHID + hbase;

  float* v1s = state;
  float* a1s = state + B_ * NHID;
  float* sps = state + 2 * B_ * NHID;
  float* vos = state + 3 * B_ * NHID;
  float* oss = vos + B_ * NOUT;

  int hact[8];
#pragma unroll
  for (int r = 0; r < 8; ++r) hact[r] = hstoremap(hbase + r);

  float v1[8], a1[8], sp[8], al[8], rh[8], ba[8];
#pragma unroll
  for (int r = 0; r < 8; ++r) {
    int h = hact[r];
    al[r] = alpha[h]; rh[r] = rho[h]; ba[r] = beta_a[h];
    if (first) { v1[r] = 0.f; a1[r] = 0.f; sp[r] = 0.f; }
    else {
      v1[r] = v1s[(size_t)b * NHID + hbase + r];
      a1[r] = a1s[(size_t)b * NHID + hbase + r];
      sp[r] = sps[(size_t)b * NHID + hbase + r];
    }
  }
  float vout = 0.f, osum = 0.f, bo = 0.f;
  if (lane < NOUT) {
    bo = beta_out[lane];
    if (!first) { vout = vos[b * NOUT + lane]; osum = oss[b * NOUT + lane]; }
  }

  int mode = first ? 0 : flags[b];
  int tle = 0;

  if (mode == 0) {
    // fast path: no spike has ever fired
    uint2 pf[8];
#pragma unroll
    for (int j = 0; j < 8; ++j) {
      int tl = (j < Tc) ? j : (Tc - 1);
      pf[j] = *(const uint2*)(ib + (size_t)tl * NHID);
    }
    bool esc = false;
    for (int tb = 0; tb < Tc && !esc; tb += 8) {
#pragma unroll
      for (int j = 0; j < 8; ++j) {
        int tl = tb + j;
        if (!esc && tl < Tc) {
          float tv[8];
#pragma unroll
          for (int r = 0; r < 8; ++r) {
            unsigned w = (r < 4) ? pf[j].x : pf[j].y;
            __hip_fp8_e4m3 q; q.__x = (unsigned char)((w >> ((r & 3) * 8)) & 255u);
            tv[r] = al[r] * v1[r] + (float)q;   // iff pre-scaled by (1-alpha)
          }
          float m01 = fmaxf(tv[0], tv[1]), m23 = fmaxf(tv[2], tv[3]);
          float m45 = fmaxf(tv[4], tv[5]), m67 = fmaxf(tv[6], tv[7]);
          float mx = fmaxf(fmaxf(m01, m23), fmaxf(m45, m67));
          if (__ballot(mx > 1.0f)) {
            esc = true; tle = tl;
          } else {
#pragma unroll
            for (int r = 0; r < 8; ++r) v1[r] = tv[r];
            int nt = (tl + 8 < Tc) ? (tl + 8) : (Tc - 1);
            pf[j] = *(const uint2*)(ib + (size_t)nt * NHID);
          }
        }
      }
    }
    if (!esc) tle = Tc;
    mode = esc ? 1 : 0;
  }

  // full path (fallback / post-first-spike)
  unsigned long long mask[8];
#pragma unroll
  for (int r = 0; r < 8; ++r) mask[r] = __ballot(sp[r] != 0.f);

  for (int tl = tle; tl < Tc; ++tl) {
    uint2 w2 = *(const uint2*)(ib + (size_t)tl * NHID);
    float iv[8];
#pragma unroll
    for (int r = 0; r < 8; ++r) {
      unsigned w = (r < 4) ? w2.x : w2.y;
      __hip_fp8_e4m3 q; q.__x = (unsigned char)((w >> ((r & 3) * 8)) & 255u);
      iv[r] = (float)q;   // = (1-alpha)*i_ff
    }
    unsigned long long anyp = mask[0] | mask[1] | mask[2] | mask[3] |
                              mask[4] | mask[5] | mask[6] | mask[7];
    if (anyp) {
      float rec[8] = {0.f,0.f,0.f,0.f,0.f,0.f,0.f,0.f};
#pragma unroll
      for (int r2 = 0; r2 < 8; ++r2) {
        unsigned long long mm = mask[r2];
        while (mm) {
          int l2 = __ffsll(mm) - 1; mm &= (mm - 1);
          int hp = hstoremap(l2 * 8 + r2);
#pragma unroll
          for (int r = 0; r < 8; ++r)
            rec[r] += wrec[(size_t)hact[r] * NHID + hp];
        }
      }
#pragma unroll
      for (int r = 0; r < 8; ++r) iv[r] += (1.0f - al[r]) * rec[r];
    }

    float s[8];
#pragma unroll
    for (int r = 0; r < 8; ++r) {
      a1[r] = rh[r] * a1[r] + ba[r] * sp[r];
      v1[r] = al[r] * v1[r] + iv[r] - a1[r];
      s[r] = (v1[r] - 1.0f > 0.0f) ? 1.0f : 0.0f;
      v1[r] -= s[r];
      sp[r] = s[r];
      mask[r] = __ballot(s[r] != 0.f);
    }

    unsigned long long anyc = mask[0] | mask[1] | mask[2] | mask[3] |
                              mask[4] | mask[5] | mask[6] | mask[7];
    if (lane < NOUT) {
      float io = 0.f;
      if (anyc) {
#pragma unroll
        for (int r2 = 0; r2 < 8; ++r2) {
          unsigned long long mm = mask[r2];
          while (mm) {
            int l2 = __ffsll(mm) - 1; mm &= (mm - 1);
            int hp = hstoremap(l2 * 8 + r2);
            io += wout[(size_t)lane * NHID + hp];
          }
        }
      }
      vout = bo * vout + (1.0f - bo) * io;
      float so = (vout - 1.0f > 0.0f) ? 1.0f : 0.0f;
      vout -= so;
      osum += vout;
    }
  }

  if (last) {
    if (lane < NOUT) dout[b * NOUT + lane] = osum / (float)T_;
  } else {
#pragma unroll
    for (int r = 0; r < 8; ++r) {
      v1s[(size_t)b * NHID + hbase + r] = v1[r];
      a1s[(size_t)b * NHID + hbase + r] = a1[r];
      sps[(size_t)b * NHID + hbase + r] = sp[r];
    }
    if (lane < NOUT) { vos[b * NOUT + lane] = vout; oss[b * NOUT + lane] = osum; }
    if (lane == 0) flags[b] = mode;
  }
}

extern "C" void kernel_launch(void* const* d_in, const int* in_sizes, int n_in,
                              void* d_out, int out_size, void* d_ws, size_t ws_size,
                              hipStream_t stream) {
  const float* x      = (const float*)d_in[0];
  const float* w1     = (const float*)d_in[1];
  const float* wrec   = (const float*)d_in[2];
  const float* wout   = (const float*)d_in[3];
  const float* alpha  = (const float*)d_in[4];
  const float* rho    = (const float*)d_in[5];
  const float* beta_a = (const float*)d_in[6];
  const float* bout   = (const float*)d_in[7];
  float* out = (float*)d_out;

  char* ws = (char*)d_ws;
  const size_t w1frag_bytes = (size_t)NKT * 16384 * 2;                       // 704 KB
  const size_t state_off = w1frag_bytes;
  const size_t state_bytes = (size_t)(3 * B_ * NHID + 2 * B_ * NOUT) * 4;
  const size_t flags_off = state_off + state_bytes;
  const size_t iff_off   = flags_off + B_ * 4;

  ushort* w1frag = (ushort*)(ws);
  float*  statep = (float*)(ws + state_off);
  int*    flagsp = (int*)(ws + flags_off);
  unsigned char* iff = (unsigned char*)(ws + iff_off);

  const size_t per_step = (size_t)B_ * NHID;  // 128 KB per timestep (fp8)
  long long avail = (long long)ws_size - (long long)iff_off;
  int Tc = (int)(avail / (long long)per_step);
  if (Tc > T_) Tc = T_;
  if (Tc < 1) Tc = 1;

  prep_kernel<<<dim3((NKT * 16384 + 255) / 256), dim3(256), 0, stream>>>(
      w1, w1frag);

  for (int t0 = 0; t0 < T_; t0 += Tc) {
    int tc = (T_ - t0 < Tc) ? (T_ - t0) : Tc;
    gemm_mfma<<<dim3(4 * tc), dim3(512), 0, stream>>>(
        x, w1frag, alpha, iff, t0, tc);
    snn_recur<<<dim3(B_), dim3(64), 0, stream>>>(
        iff, wrec, wout, alpha, rho, beta_a, bout, statep, flagsp, out,
        tc, (t0 == 0) ? 1 : 0, (t0 + tc >= T_) ? 1 : 0);
  }
}

// Round 11
// 105.006 us; speedup vs baseline: 2.6252x; 1.3405x over previous
//
#include <hip/hip_runtime.h>
#include <hip/hip_bf16.h>
#include <hip/hip_fp8.h>

// SNN forward, round 11: traffic-minimized fp8 GEMM.
// Model (fits R5-R10): dur ~= total vector-load bytes / ~6.8 TB/s (per-CU cap
// ~10-11 B/cyc incl. cache hits). So: fp8 B (w1 x16 prescale), fp8 A (HW cvt),
// BM=128 full-N blocks (x read once, B 416KB x 500), tri-buffered B +
// depth-2 A with exact FIFO vmcnt(4) one-iteration-cover, 1 barrier/iter.

#define B_    256
#define T_    250
#define NIN   700
#define NHID  512
#define NOUT  20
#define NKT   24          // K-tiles of 32 (padded 768; tiles 22,23 zero-B)
#define NSLAB 26          // +2 dummy prefetch slabs

typedef __attribute__((ext_vector_type(4))) float f32x4;

static __device__ __forceinline__ unsigned pack_fp8x4(float f0, float f1,
                                                      float f2, float f3) {
#if __has_builtin(__builtin_amdgcn_cvt_pk_fp8_f32)
  int u = __builtin_amdgcn_cvt_pk_fp8_f32(f0, f1, 0, false);
  u = __builtin_amdgcn_cvt_pk_fp8_f32(f2, f3, u, true);
  return (unsigned)u;
#else
  __hip_fp8_e4m3 q0(f0), q1(f1), q2(f2), q3(f3);
  return (unsigned)q0.__x | ((unsigned)q1.__x << 8) |
         ((unsigned)q2.__x << 16) | ((unsigned)q3.__x << 24);
#endif
}
static __device__ __forceinline__ void gload_lds16(const void* g, void* l) {
  __builtin_amdgcn_global_load_lds(
      (const __attribute__((address_space(1))) unsigned*)g,
      (__attribute__((address_space(3))) unsigned*)l, 16, 0, 0);
}
static __device__ __forceinline__ long u2l(uint2 v) {
  union { uint2 u; long l; } c; c.u = v; return c.l;
}
// storage slot s (0..511) -> actual h:  s = wc*128 + lm*8 + q  <->
// h = wc*128 + q*16 + lm   (q = s&7, lm = (s>>3)&15)
static __device__ __forceinline__ int hstoremap(int s) {
  return (s & 0x180) | (((s & 7) << 4) | ((s >> 3) & 15));
}

// ---------------- prep: w1 -> fp8 fragment slabs (x16 prescale) ----------------
// slab kt (16KB): [cb 0..31][lane 0..63][8 bytes]
// col = cb*16 + (lane&15); k = kt*32 + (lane>>4)*8 + e
__global__ __launch_bounds__(256) void prep_kernel(
    const float* __restrict__ w1, unsigned char* __restrict__ w1f8) {
  int i = blockIdx.x * 256 + threadIdx.x;
  if (i >= NSLAB * 16384) return;
  int e    = i & 7;
  int lane = (i >> 3) & 63;
  int cb   = (i >> 9) & 31;
  int slab = i >> 14;
  int col = cb * 16 + (lane & 15);
  int k   = slab * 32 + (lane >> 4) * 8 + e;
  unsigned char v = 0;
  if (slab < NKT && k < NIN) {
    __hip_fp8_e4m3 q(16.0f * w1[(size_t)col * NIN + k]);
    v = q.__x;
  }
  w1f8[i] = v;
}

// ---------------- fp8 MFMA GEMM ----------------
// grid = 2*tc; block 512 thr / 8 waves (2x4), tile 128(m) x 512(h), BK=32.
__global__ __launch_bounds__(512) void gemm_mfma(
    const float* __restrict__ x, const unsigned char* __restrict__ w1f8,
    const float* __restrict__ alpha, unsigned char* __restrict__ iff,
    int t0, int tc) {
  __shared__ __align__(16) char Al[2][4096];    // [rb 0..7][lane][8B], XOR-swz
  __shared__ __align__(16) char Bl[3][16384];   // [cb 0..31][lane][8B]

  int tid = threadIdx.x, lane = tid & 63, wave = tid >> 6;
  int wr = wave >> 2, wc = wave & 3;            // 2 x 4 wave grid (64x128)
  int lm = lane & 15, lk = lane >> 4;
  int m0 = blockIdx.x * 128;

  // A stager: thread -> (row srow 0..127, k-octet kq 0..3)
  int srow = tid >> 2, kq = tid & 3;
  int m = m0 + srow;
  int bb = m / tc;
  int xrow = bb * T_ + t0 + (m - bb * tc);
  const float* ap = x + (size_t)xrow * NIN;
  int wofs = (srow >> 4) * 512 + ((((srow & 15) + 16 * kq) * 8) ^ (kq << 4));

  f32x4 acc[4][8];
#pragma unroll
  for (int i = 0; i < 4; ++i)
#pragma unroll
    for (int j = 0; j < 8; ++j) acc[i][j] = (f32x4){0.f, 0.f, 0.f, 0.f};

  float4 sA0, sA1, sB0, sB1;

#define LOADA(D0, D1, KT) do { int k0_ = (KT) * 32 + kq * 8;                 \
    int a0_ = (k0_ + 4 <= NIN) ? k0_ : 0;                                    \
    int a1_ = (k0_ + 8 <= NIN) ? k0_ + 4 : 0;                                \
    D0 = *(const float4*)(ap + a0_);                                         \
    D1 = *(const float4*)(ap + a1_); } while (0)

#define WRITEA(BUF, S0, S1) do {                                             \
    uint2 w_;                                                                \
    w_.x = pack_fp8x4(S0.x, S0.y, S0.z, S0.w);                               \
    w_.y = pack_fp8x4(S1.x, S1.y, S1.z, S1.w);                               \
    *(uint2*)(&Al[BUF][wofs]) = w_; } while (0)

#define STAGEB(KT) do {                                                      \
    const char* gs_ = (const char*)w1f8 + ((size_t)(KT) << 14);              \
    char* ls_ = Bl[(KT) % 3];                                                \
    gload_lds16(gs_ + (wave * 2 + 0) * 1024 + lane * 16,                     \
                ls_ + (wave * 2 + 0) * 1024);                                \
    gload_lds16(gs_ + (wave * 2 + 1) * 1024 + lane * 16,                     \
                ls_ + (wave * 2 + 1) * 1024); } while (0)

  // prologue: B(0)+A(0) -> drain -> write Al[0]; issue B(1),A(1) (stay out)
  STAGEB(0);
  LOADA(sA0, sA1, 0);
  asm volatile("s_waitcnt vmcnt(0)" ::: "memory");
  __builtin_amdgcn_sched_barrier(0);
  WRITEA(0, sA0, sA1);
  STAGEB(1);
  LOADA(sB0, sB1, 1);
  asm volatile("s_waitcnt lgkmcnt(0)" ::: "memory");
  __builtin_amdgcn_s_barrier();
  __builtin_amdgcn_sched_barrier(0);

  // steady state: entering iter kt: LDS has A(kt),B(kt); outstanding FIFO =
  // {B(kt+1), A(kt+1)}. vmcnt(4) drains them (issued one full iter earlier).
#pragma unroll
  for (int kt = 0; kt < NKT; ++kt) {
    STAGEB(kt + 2);                                   // dummy slabs at 24,25
    if ((kt & 1) == 0) { LOADA(sA0, sA1, kt + 2); }
    else               { LOADA(sB0, sB1, kt + 2); }
    asm volatile("s_waitcnt vmcnt(4)" ::: "memory");
    __builtin_amdgcn_sched_barrier(0);
    if ((kt & 1) == 0) { WRITEA((kt + 1) & 1, sB0, sB1); }
    else               { WRITEA((kt + 1) & 1, sA0, sA1); }
    // fragments + MFMA
    {
      const char* Ab = Al[kt & 1];
      const char* Bb = Bl[kt % 3];
      int aswz = (lane * 8) ^ ((lane >> 4) << 4);
      long af[4], bf[8];
#pragma unroll
      for (int i = 0; i < 4; ++i)
        af[i] = u2l(*(const uint2*)(&Ab[(wr * 4 + i) * 512 + aswz]));
#pragma unroll
      for (int j = 0; j < 8; ++j)
        bf[j] = u2l(*(const uint2*)(&Bb[(wc * 8 + j) * 512 + lane * 8]));
      __builtin_amdgcn_s_setprio(1);
#pragma unroll
      for (int i = 0; i < 4; ++i)
#pragma unroll
        for (int j = 0; j < 8; ++j)
          acc[i][j] = __builtin_amdgcn_mfma_f32_16x16x32_fp8_fp8(
              af[i], bf[j], acc[i][j], 0, 0, 0);
      __builtin_amdgcn_s_setprio(0);
    }
    asm volatile("s_waitcnt lgkmcnt(0)" ::: "memory");
    __builtin_amdgcn_s_barrier();
    __builtin_amdgcn_sched_barrier(0);
  }
#undef LOADA
#undef WRITEA
#undef STAGEB

  // epilogue: scale by (1-alpha)/16, pack 8 fp8 -> uint2 at permuted slot
  float scl[8];
#pragma unroll
  for (int j = 0; j < 8; ++j)
    scl[j] = (1.0f - alpha[wc * 128 + j * 16 + lm]) * 0.0625f;
#pragma unroll
  for (int i = 0; i < 4; ++i) {
#pragma unroll
    for (int r = 0; r < 4; ++r) {
      int row = m0 + wr * 64 + i * 16 + lk * 4 + r;
      uint2 w_;
      w_.x = pack_fp8x4(acc[i][0][r] * scl[0], acc[i][1][r] * scl[1],
                        acc[i][2][r] * scl[2], acc[i][3][r] * scl[3]);
      w_.y = pack_fp8x4(acc[i][4][r] * scl[4], acc[i][5][r] * scl[5],
                        acc[i][6][r] * scl[6], acc[i][7][r] * scl[7]);
      *(uint2*)(iff + (size_t)row * NHID + wc * 128 + lm * 8) = w_;
    }
  }
}

// ---------------- fused recurrence (R10 structure, new hstoremap) ----------------
__global__ __launch_bounds__(64) void snn_recur(
    const unsigned char* __restrict__ iff, const float* __restrict__ wrec,
    const float* __restrict__ wout,
    const float* __restrict__ alpha, const float* __restrict__ rho,
    const float* __restrict__ beta_a, const float* __restrict__ beta_out,
    float* __restrict__ state, int* __restrict__ flags,
    float* __restrict__ dout, int Tc, int first, int last) {
  int lane = threadIdx.x;
  int b = blockIdx.x;
  int hbase = lane * 8;
  const unsigned char* ib = iff + (size_t)b * Tc * NHID + hbase;

  float* v1s = state;
  float* a1s = state + B_ * NHID;
  float* sps = state + 2 * B_ * NHID;
  float* vos = state + 3 * B_ * NHID;
  float* oss = vos + B_ * NOUT;

  int hact[8];
#pragma unroll
  for (int r = 0; r < 8; ++r) hact[r] = hstoremap(hbase + r);

  float v1[8], a1[8], sp[8], al[8], rh[8], ba[8];
#pragma unroll
  for (int r = 0; r < 8; ++r) {
    int h = hact[r];
    al[r] = alpha[h]; rh[r] = rho[h]; ba[r] = beta_a[h];
    if (first) { v1[r] = 0.f; a1[r] = 0.f; sp[r] = 0.f; }
    else {
      v1[r] = v1s[(size_t)b * NHID + hbase + r];
      a1[r] = a1s[(size_t)b * NHID + hbase + r];
      sp[r] = sps[(size_t)b * NHID + hbase + r];
    }
  }
  float vout = 0.f, osum = 0.f, bo = 0.f;
  if (lane < NOUT) {
    bo = beta_out[lane];
    if (!first) { vout = vos[b * NOUT + lane]; osum = oss[b * NOUT + lane]; }
  }

  int mode = first ? 0 : flags[b];
  int tle = 0;

  if (mode == 0) {
    uint2 pf[8];
#pragma unroll
    for (int j = 0; j < 8; ++j) {
      int tl = (j < Tc) ? j : (Tc - 1);
      pf[j] = *(const uint2*)(ib + (size_t)tl * NHID);
    }
    bool esc = false;
    for (int tb = 0; tb < Tc && !esc; tb += 8) {
#pragma unroll
      for (int j = 0; j < 8; ++j) {
        int tl = tb + j;
        if (!esc && tl < Tc) {
          float tv[8];
#pragma unroll
          for (int r = 0; r < 8; ++r) {
            unsigned w = (r < 4) ? pf[j].x : pf[j].y;
            __hip_fp8_e4m3 q; q.__x = (unsigned char)((w >> ((r & 3) * 8)) & 255u);
            tv[r] = al[r] * v1[r] + (float)q;   // iff pre-scaled by (1-alpha)
          }
          float m01 = fmaxf(tv[0], tv[1]), m23 = fmaxf(tv[2], tv[3]);
          float m45 = fmaxf(tv[4], tv[5]), m67 = fmaxf(tv[6], tv[7]);
          float mx = fmaxf(fmaxf(m01, m23), fmaxf(m45, m67));
          if (__ballot(mx > 1.0f)) {
            esc = true; tle = tl;
          } else {
#pragma unroll
            for (int r = 0; r < 8; ++r) v1[r] = tv[r];
            int nt = (tl + 8 < Tc) ? (tl + 8) : (Tc - 1);
            pf[j] = *(const uint2*)(ib + (size_t)nt * NHID);
          }
        }
      }
    }
    if (!esc) tle = Tc;
    mode = esc ? 1 : 0;
  }

  unsigned long long mask[8];
#pragma unroll
  for (int r = 0; r < 8; ++r) mask[r] = __ballot(sp[r] != 0.f);

  for (int tl = tle; tl < Tc; ++tl) {
    uint2 w2 = *(const uint2*)(ib + (size_t)tl * NHID);
    float iv[8];
#pragma unroll
    for (int r = 0; r < 8; ++r) {
      unsigned w = (r < 4) ? w2.x : w2.y;
      __hip_fp8_e4m3 q; q.__x = (unsigned char)((w >> ((r & 3) * 8)) & 255u);
      iv[r] = (float)q;
    }
    unsigned long long anyp = mask[0] | mask[1] | mask[2] | mask[3] |
                              mask[4] | mask[5] | mask[6] | mask[7];
    if (anyp) {
      float rec[8] = {0.f,0.f,0.f,0.f,0.f,0.f,0.f,0.f};
#pragma unroll
      for (int r2 = 0; r2 < 8; ++r2) {
        unsigned long long mm = mask[r2];
        while (mm) {
          int l2 = __ffsll(mm) - 1; mm &= (mm - 1);
          int hp = hstoremap(l2 * 8 + r2);
#pragma unroll
          for (int r = 0; r < 8; ++r)
            rec[r] += wrec[(size_t)hact[r] * NHID + hp];
        }
      }
#pragma unroll
      for (int r = 0; r < 8; ++r) iv[r] += (1.0f - al[r]) * rec[r];
    }

    float s[8];
#pragma unroll
    for (int r = 0; r < 8; ++r) {
      a1[r] = rh[r] * a1[r] + ba[r] * sp[r];
      v1[r] = al[r] * v1[r] + iv[r] - a1[r];
      s[r] = (v1[r] - 1.0f > 0.0f) ? 1.0f : 0.0f;
      v1[r] -= s[r];
      sp[r] = s[r];
      mask[r] = __ballot(s[r] != 0.f);
    }

    unsigned long long anyc = mask[0] | mask[1] | mask[2] | mask[3] |
                              mask[4] | mask[5] | mask[6] | mask[7];
    if (lane < NOUT) {
      float io = 0.f;
      if (anyc) {
#pragma unroll
        for (int r2 = 0; r2 < 8; ++r2) {
          unsigned long long mm = mask[r2];
          while (mm) {
            int l2 = __ffsll(mm) - 1; mm &= (mm - 1);
            int hp = hstoremap(l2 * 8 + r2);
            io += wout[(size_t)lane * NHID + hp];
          }
        }
      }
      vout = bo * vout + (1.0f - bo) * io;
      float so = (vout - 1.0f > 0.0f) ? 1.0f : 0.0f;
      vout -= so;
      osum += vout;
    }
  }

  if (last) {
    if (lane < NOUT) dout[b * NOUT + lane] = osum / (float)T_;
  } else {
#pragma unroll
    for (int r = 0; r < 8; ++r) {
      v1s[(size_t)b * NHID + hbase + r] = v1[r];
      a1s[(size_t)b * NHID + hbase + r] = a1[r];
      sps[(size_t)b * NHID + hbase + r] = sp[r];
    }
    if (lane < NOUT) { vos[b * NOUT + lane] = vout; oss[b * NOUT + lane] = osum; }
    if (lane == 0) flags[b] = mode;
  }
}

extern "C" void kernel_launch(void* const* d_in, const int* in_sizes, int n_in,
                              void* d_out, int out_size, void* d_ws, size_t ws_size,
                              hipStream_t stream) {
  const float* x      = (const float*)d_in[0];
  const float* w1     = (const float*)d_in[1];
  const float* wrec   = (const float*)d_in[2];
  const float* wout   = (const float*)d_in[3];
  const float* alpha  = (const float*)d_in[4];
  const float* rho    = (const float*)d_in[5];
  const float* beta_a = (const float*)d_in[6];
  const float* bout   = (const float*)d_in[7];
  float* out = (float*)d_out;

  char* ws = (char*)d_ws;
  const size_t w1f8_bytes = (size_t)NSLAB * 16384;                           // 416 KB
  const size_t state_off = w1f8_bytes;
  const size_t state_bytes = (size_t)(3 * B_ * NHID + 2 * B_ * NOUT) * 4;
  const size_t flags_off = state_off + state_bytes;
  const size_t iff_off   = flags_off + B_ * 4;

  unsigned char* w1f8 = (unsigned char*)(ws);
  float*  statep = (float*)(ws + state_off);
  int*    flagsp = (int*)(ws + flags_off);
  unsigned char* iff = (unsigned char*)(ws + iff_off);

  const size_t per_step = (size_t)B_ * NHID;  // 128 KB per timestep (fp8)
  long long avail = (long long)ws_size - (long long)iff_off;
  int Tc = (int)(avail / (long long)per_step);
  if (Tc > T_) Tc = T_;
  if (Tc < 1) Tc = 1;

  prep_kernel<<<dim3((NSLAB * 16384 + 255) / 256), dim3(256), 0, stream>>>(
      w1, w1f8);

  for (int t0 = 0; t0 < T_; t0 += Tc) {
    int tc = (T_ - t0 < Tc) ? (T_ - t0) : Tc;
    gemm_mfma<<<dim3(2 * tc), dim3(512), 0, stream>>>(
        x, w1f8, alpha, iff, t0, tc);
    snn_recur<<<dim3(B_), dim3(64), 0, stream>>>(
        iff, wrec, wout, alpha, rho, beta_a, bout, statep, flagsp, out,
        tc, (t0 == 0) ? 1 : 0, (t0 + tc >= T_) ? 1 : 0);
  }
}

// Round 12
// 94.358 us; speedup vs baseline: 2.9214x; 1.1128x over previous
//
#include <hip/hip_runtime.h>
#include <hip/hip_bf16.h>
#include <hip/hip_fp8.h>

// SNN forward, round 12: fp8 GEMM, 16-wave blocks for occupancy.
// BM=128 x BN=512 (x read once), 1024 thr / 16 waves (2x8), wave-tile 64x64
// (acc=64 -> <=128 VGPR -> 4 waves/SIMD -> 16 waves/CU, 2x R11). B: fp8
// fragment slabs via global_load_lds, tri-buffered; A: f32->fp8 in-register,
// double-buffered LDS; exact FIFO vmcnt(2) one-iteration cover; 1 barrier/iter.

#define B_    256
#define T_    250
#define NIN   700
#define NHID  512
#define NOUT  20
#define NKT   22          // K-tiles of 32 (704 = 22*32)
#define NSLAB 24          // +2 dummy prefetch slabs

typedef __attribute__((ext_vector_type(4))) float f32x4;

static __device__ __forceinline__ unsigned pack_fp8x4(float f0, float f1,
                                                      float f2, float f3) {
#if __has_builtin(__builtin_amdgcn_cvt_pk_fp8_f32)
  int u = __builtin_amdgcn_cvt_pk_fp8_f32(f0, f1, 0, false);
  u = __builtin_amdgcn_cvt_pk_fp8_f32(f2, f3, u, true);
  return (unsigned)u;
#else
  __hip_fp8_e4m3 q0(f0), q1(f1), q2(f2), q3(f3);
  return (unsigned)q0.__x | ((unsigned)q1.__x << 8) |
         ((unsigned)q2.__x << 16) | ((unsigned)q3.__x << 24);
#endif
}
static __device__ __forceinline__ void gload_lds16(const void* g, void* l) {
  __builtin_amdgcn_global_load_lds(
      (const __attribute__((address_space(1))) unsigned*)g,
      (__attribute__((address_space(3))) unsigned*)l, 16, 0, 0);
}
static __device__ __forceinline__ long u2l(uint2 v) {
  union { uint2 u; long l; } c; c.u = v; return c.l;
}
// storage slot s (0..511) -> actual h: within each 64-chunk s6 = lm*4+j <->
// h6 = j*16+lm
static __device__ __forceinline__ int hstoremap(int s) {
  return (s & 0x1C0) | ((s & 3) << 4) | ((s >> 2) & 15);
}

// ---------------- prep: w1 -> fp8 fragment slabs (x16 prescale) ----------------
// slab kt (16KB): [cb 0..31][lane 0..63][8 bytes]
// col = cb*16 + (lane&15); k = kt*32 + (lane>>4)*8 + e
__global__ __launch_bounds__(256) void prep_kernel(
    const float* __restrict__ w1, unsigned char* __restrict__ w1f8) {
  int i = blockIdx.x * 256 + threadIdx.x;
  if (i >= NSLAB * 16384) return;
  int e    = i & 7;
  int lane = (i >> 3) & 63;
  int cb   = (i >> 9) & 31;
  int slab = i >> 14;
  int col = cb * 16 + (lane & 15);
  int k   = slab * 32 + (lane >> 4) * 8 + e;
  unsigned char v = 0;
  if (slab < NKT && k < NIN) {
    __hip_fp8_e4m3 q(16.0f * w1[(size_t)col * NIN + k]);
    v = q.__x;
  }
  w1f8[i] = v;
}

// ---------------- fp8 MFMA GEMM ----------------
// grid = 2*tc; block 1024 thr / 16 waves (2x8), tile 128(m) x 512(h), BK=32.
__global__ __launch_bounds__(1024, 4) void gemm_mfma(
    const float* __restrict__ x, const unsigned char* __restrict__ w1f8,
    const float* __restrict__ alpha, unsigned char* __restrict__ iff,
    int t0, int tc) {
  __shared__ __align__(16) char Al[2][4096];    // fp8 A tile, frag order
  __shared__ __align__(16) char Bl[3][16384];   // fp8 B slabs, frag order

  int tid = threadIdx.x, lane = tid & 63, wave = tid >> 6;
  int wr = wave >> 3, wc = wave & 7;            // 2 x 8 wave grid (64x64)
  int lm = lane & 15, lk = lane >> 4;
  int m0 = blockIdx.x * 128;

  // A stager: thread -> (row srow 0..127, k-quad kq 0..7: 4 f32 each)
  int srow = tid >> 3, kq = tid & 7;
  int m = m0 + srow;
  int bb = m / tc;
  int xrow = bb * T_ + t0 + (m - bb * tc);
  const float* ap = x + (size_t)xrow * NIN;
  int wofs = (srow >> 4) * 512
           + ((((srow & 15) + 16 * (kq >> 1)) * 8) ^ ((kq >> 1) << 4))
           + ((kq & 1) << 2);

  f32x4 acc[4][4];
#pragma unroll
  for (int i = 0; i < 4; ++i)
#pragma unroll
    for (int j = 0; j < 4; ++j) acc[i][j] = (f32x4){0.f, 0.f, 0.f, 0.f};

  float4 sA, sB;   // A-stage ping-pong (loaded iter kt, written iter kt+1)

#define LOADA(D, KT) do { int k0_ = (KT) * 32 + kq * 4;                      \
    int a0_ = (k0_ + 4 <= NIN) ? k0_ : 0;                                    \
    D = *(const float4*)(ap + a0_); } while (0)

#define WRITEA(BUF, S) do {                                                  \
    *(unsigned*)(&Al[BUF][wofs]) = pack_fp8x4(S.x, S.y, S.z, S.w);           \
  } while (0)

#define STAGEB(KT) do {                                                      \
    const char* gs_ = (const char*)w1f8 + ((size_t)(KT) << 14)               \
                    + wave * 1024 + lane * 16;                               \
    gload_lds16(gs_, Bl[(KT) % 3] + wave * 1024); } while (0)

  // prologue: B(0)+A(0) -> drain -> write Al[0]; issue B(1)+A(1) (stay out)
  STAGEB(0);
  LOADA(sA, 0);
  asm volatile("s_waitcnt vmcnt(0)" ::: "memory");
  __builtin_amdgcn_sched_barrier(0);
  WRITEA(0, sA);
  STAGEB(1);
  LOADA(sB, 1);
  asm volatile("s_waitcnt lgkmcnt(0)" ::: "memory");
  __builtin_amdgcn_s_barrier();
  __builtin_amdgcn_sched_barrier(0);

  // steady state entering iter kt: LDS has A(kt),B(kt); outstanding FIFO =
  // {B(kt+1), A(kt+1)} (2 vm ops). vmcnt(2) drains them after issuing kt+2.
#pragma unroll
  for (int kt = 0; kt < NKT; ++kt) {
    STAGEB(kt + 2);                               // dummies at 22,23 are zero
    if ((kt & 1) == 0) { LOADA(sA, kt + 2); }
    else               { LOADA(sB, kt + 2); }
    asm volatile("s_waitcnt vmcnt(2)" ::: "memory");
    __builtin_amdgcn_sched_barrier(0);
    if ((kt & 1) == 0) { WRITEA((kt + 1) & 1, sB); }
    else               { WRITEA((kt + 1) & 1, sA); }
    // fragments + MFMA
    {
      const char* Ab = Al[kt & 1];
      const char* Bb = Bl[kt % 3];
      int aswz = (lane * 8) ^ (lk << 4);
      long af[4], bf[4];
#pragma unroll
      for (int i = 0; i < 4; ++i)
        af[i] = u2l(*(const uint2*)(&Ab[(wr * 4 + i) * 512 + aswz]));
#pragma unroll
      for (int j = 0; j < 4; ++j)
        bf[j] = u2l(*(const uint2*)(&Bb[(wc * 4 + j) * 512 + lane * 8]));
      __builtin_amdgcn_s_setprio(1);
#pragma unroll
      for (int i = 0; i < 4; ++i)
#pragma unroll
        for (int j = 0; j < 4; ++j)
          acc[i][j] = __builtin_amdgcn_mfma_f32_16x16x32_fp8_fp8(
              af[i], bf[j], acc[i][j], 0, 0, 0);
      __builtin_amdgcn_s_setprio(0);
    }
    asm volatile("s_waitcnt lgkmcnt(0)" ::: "memory");
    __builtin_amdgcn_s_barrier();
    __builtin_amdgcn_sched_barrier(0);
  }
#undef LOADA
#undef WRITEA
#undef STAGEB

  // epilogue: scale by (1-alpha)/16, pack 4 fp8 -> u32 at permuted slot
  float scl[4];
#pragma unroll
  for (int j = 0; j < 4; ++j)
    scl[j] = (1.0f - alpha[wc * 64 + j * 16 + lm]) * 0.0625f;
#pragma unroll
  for (int i = 0; i < 4; ++i) {
#pragma unroll
    for (int r = 0; r < 4; ++r) {
      int row = m0 + wr * 64 + i * 16 + lk * 4 + r;
      unsigned u = pack_fp8x4(acc[i][0][r] * scl[0], acc[i][1][r] * scl[1],
                              acc[i][2][r] * scl[2], acc[i][3][r] * scl[3]);
      *(unsigned*)(iff + (size_t)row * NHID + wc * 64 + lm * 4) = u;
    }
  }
}

// ---------------- fused recurrence (R11 structure, R8 hstoremap) ----------------
__global__ __launch_bounds__(64) void snn_recur(
    const unsigned char* __restrict__ iff, const float* __restrict__ wrec,
    const float* __restrict__ wout,
    const float* __restrict__ alpha, const float* __restrict__ rho,
    const float* __restrict__ beta_a, const float* __restrict__ beta_out,
    float* __restrict__ state, int* __restrict__ flags,
    float* __restrict__ dout, int Tc, int first, int last) {
  int lane = threadIdx.x;
  int b = blockIdx.x;
  int hbase = lane * 8;
  const unsigned char* ib = iff + (size_t)b * Tc * NHID + hbase;

  float* v1s = state;
  float* a1s = state + B_ * NHID;
  float* sps = state + 2 * B_ * NHID;
  float* vos = state + 3 * B_ * NHID;
  float* oss = vos + B_ * NOUT;

  int hact[8];
#pragma unroll
  for (int r = 0; r < 8; ++r) hact[r] = hstoremap(hbase + r);

  float v1[8], a1[8], sp[8], al[8], rh[8], ba[8];
#pragma unroll
  for (int r = 0; r < 8; ++r) {
    int h = hact[r];
    al[r] = alpha[h]; rh[r] = rho[h]; ba[r] = beta_a[h];
    if (first) { v1[r] = 0.f; a1[r] = 0.f; sp[r] = 0.f; }
    else {
      v1[r] = v1s[(size_t)b * NHID + hbase + r];
      a1[r] = a1s[(size_t)b * NHID + hbase + r];
      sp[r] = sps[(size_t)b * NHID + hbase + r];
    }
  }
  float vout = 0.f, osum = 0.f, bo = 0.f;
  if (lane < NOUT) {
    bo = beta_out[lane];
    if (!first) { vout = vos[b * NOUT + lane]; osum = oss[b * NOUT + lane]; }
  }

  int mode = first ? 0 : flags[b];
  int tle = 0;

  if (mode == 0) {
    uint2 pf[8];
#pragma unroll
    for (int j = 0; j < 8; ++j) {
      int tl = (j < Tc) ? j : (Tc - 1);
      pf[j] = *(const uint2*)(ib + (size_t)tl * NHID);
    }
    bool esc = false;
    for (int tb = 0; tb < Tc && !esc; tb += 8) {
#pragma unroll
      for (int j = 0; j < 8; ++j) {
        int tl = tb + j;
        if (!esc && tl < Tc) {
          float tv[8];
#pragma unroll
          for (int r = 0; r < 8; ++r) {
            unsigned w = (r < 4) ? pf[j].x : pf[j].y;
            __hip_fp8_e4m3 q; q.__x = (unsigned char)((w >> ((r & 3) * 8)) & 255u);
            tv[r] = al[r] * v1[r] + (float)q;   // iff pre-scaled by (1-alpha)
          }
          float m01 = fmaxf(tv[0], tv[1]), m23 = fmaxf(tv[2], tv[3]);
          float m45 = fmaxf(tv[4], tv[5]), m67 = fmaxf(tv[6], tv[7]);
          float mx = fmaxf(fmaxf(m01, m23), fmaxf(m45, m67));
          if (__ballot(mx > 1.0f)) {
            esc = true; tle = tl;
          } else {
#pragma unroll
            for (int r = 0; r < 8; ++r) v1[r] = tv[r];
            int nt = (tl + 8 < Tc) ? (tl + 8) : (Tc - 1);
            pf[j] = *(const uint2*)(ib + (size_t)nt * NHID);
          }
        }
      }
    }
    if (!esc) tle = Tc;
    mode = esc ? 1 : 0;
  }

  unsigned long long mask[8];
#pragma unroll
  for (int r = 0; r < 8; ++r) mask[r] = __ballot(sp[r] != 0.f);

  for (int tl = tle; tl < Tc; ++tl) {
    uint2 w2 = *(const uint2*)(ib + (size_t)tl * NHID);
    float iv[8];
#pragma unroll
    for (int r = 0; r < 8; ++r) {
      unsigned w = (r < 4) ? w2.x : w2.y;
      __hip_fp8_e4m3 q; q.__x = (unsigned char)((w >> ((r & 3) * 8)) & 255u);
      iv[r] = (float)q;
    }
    unsigned long long anyp = mask[0] | mask[1] | mask[2] | mask[3] |
                              mask[4] | mask[5] | mask[6] | mask[7];
    if (anyp) {
      float rec[8] = {0.f,0.f,0.f,0.f,0.f,0.f,0.f,0.f};
#pragma unroll
      for (int r2 = 0; r2 < 8; ++r2) {
        unsigned long long mm = mask[r2];
        while (mm) {
          int l2 = __ffsll(mm) - 1; mm &= (mm - 1);
          int hp = hstoremap(l2 * 8 + r2);
#pragma unroll
          for (int r = 0; r < 8; ++r)
            rec[r] += wrec[(size_t)hact[r] * NHID + hp];
        }
      }
#pragma unroll
      for (int r = 0; r < 8; ++r) iv[r] += (1.0f - al[r]) * rec[r];
    }

    float s[8];
#pragma unroll
    for (int r = 0; r < 8; ++r) {
      a1[r] = rh[r] * a1[r] + ba[r] * sp[r];
      v1[r] = al[r] * v1[r] + iv[r] - a1[r];
      s[r] = (v1[r] - 1.0f > 0.0f) ? 1.0f : 0.0f;
      v1[r] -= s[r];
      sp[r] = s[r];
      mask[r] = __ballot(s[r] != 0.f);
    }

    unsigned long long anyc = mask[0] | mask[1] | mask[2] | mask[3] |
                              mask[4] | mask[5] | mask[6] | mask[7];
    if (lane < NOUT) {
      float io = 0.f;
      if (anyc) {
#pragma unroll
        for (int r2 = 0; r2 < 8; ++r2) {
          unsigned long long mm = mask[r2];
          while (mm) {
            int l2 = __ffsll(mm) - 1; mm &= (mm - 1);
            int hp = hstoremap(l2 * 8 + r2);
            io += wout[(size_t)lane * NHID + hp];
          }
        }
      }
      vout = bo * vout + (1.0f - bo) * io;
      float so = (vout - 1.0f > 0.0f) ? 1.0f : 0.0f;
      vout -= so;
      osum += vout;
    }
  }

  if (last) {
    if (lane < NOUT) dout[b * NOUT + lane] = osum / (float)T_;
  } else {
#pragma unroll
    for (int r = 0; r < 8; ++r) {
      v1s[(size_t)b * NHID + hbase + r] = v1[r];
      a1s[(size_t)b * NHID + hbase + r] = a1[r];
      sps[(size_t)b * NHID + hbase + r] = sp[r];
    }
    if (lane < NOUT) { vos[b * NOUT + lane] = vout; oss[b * NOUT + lane] = osum; }
    if (lane == 0) flags[b] = mode;
  }
}

extern "C" void kernel_launch(void* const* d_in, const int* in_sizes, int n_in,
                              void* d_out, int out_size, void* d_ws, size_t ws_size,
                              hipStream_t stream) {
  const float* x      = (const float*)d_in[0];
  const float* w1     = (const float*)d_in[1];
  const float* wrec   = (const float*)d_in[2];
  const float* wout   = (const float*)d_in[3];
  const float* alpha  = (const float*)d_in[4];
  const float* rho    = (const float*)d_in[5];
  const float* beta_a = (const float*)d_in[6];
  const float* bout   = (const float*)d_in[7];
  float* out = (float*)d_out;

  char* ws = (char*)d_ws;
  const size_t w1f8_bytes = (size_t)NSLAB * 16384;                           // 384 KB
  const size_t state_off = w1f8_bytes;
  const size_t state_bytes = (size_t)(3 * B_ * NHID + 2 * B_ * NOUT) * 4;
  const size_t flags_off = state_off + state_bytes;
  const size_t iff_off   = flags_off + B_ * 4;

  unsigned char* w1f8 = (unsigned char*)(ws);
  float*  statep = (float*)(ws + state_off);
  int*    flagsp = (int*)(ws + flags_off);
  unsigned char* iff = (unsigned char*)(ws + iff_off);

  const size_t per_step = (size_t)B_ * NHID;  // 128 KB per timestep (fp8)
  long long avail = (long long)ws_size - (long long)iff_off;
  int Tc = (int)(avail / (long long)per_step);
  if (Tc > T_) Tc = T_;
  if (Tc < 1) Tc = 1;

  prep_kernel<<<dim3((NSLAB * 16384 + 255) / 256), dim3(256), 0, stream>>>(
      w1, w1f8);

  for (int t0 = 0; t0 < T_; t0 += Tc) {
    int tc = (T_ - t0 < Tc) ? (T_ - t0) : Tc;
    gemm_mfma<<<dim3(2 * tc), dim3(1024), 0, stream>>>(
        x, w1f8, alpha, iff, t0, tc);
    snn_recur<<<dim3(B_), dim3(64), 0, stream>>>(
        iff, wrec, wout, alpha, rho, beta_a, bout, statep, flagsp, out,
        tc, (t0 == 0) ? 1 : 0, (t0 + tc >= T_) ? 1 : 0);
  }
}